// Round 14
// baseline (789.412 us; speedup 1.0000x reference)
//
#include <hip/hip_runtime.h>

// VectorQuantizer (VAR-style multi-scale residual VQ) forward on gfx950.
// R20: megakernel + HIERARCHICAL arrival barrier. R18 (shared-flag poll)
// and R19 (per-block flag poll) both measured ~20us/barrier -> the cost is
// the part they SHARE: 512 blocks atomicAdd ONE arrival counter =
// ~30ns/serialized same-line RMW x 512 = 15-20us (same pathology as R14's
// argmax atomics and R17's loss atomics; third instance). Fix: 2-level
// arrival -- 32 group counters (16 blocks each, 128B-spaced, parallel
// across lines) -> group-last bumps global (32 serialized) -> global-last
// releases via R19's parallel per-block flag exchange. Monotonic targets
// (bar*16 group, bar*32 global), no resets; fences unchanged (protocol
// validated by R18/R19 passing). Phase bodies byte-identical to R17-R19.
// Decision rule: if total >= 520us, revert to R17 multi-dispatch as final.

#define B_ 32
#define C_ 64
#define L_ 512
#define V_ 8192
#define NBLK 512

typedef _Float16 half8 __attribute__((ext_vector_type(8)));
typedef float f32x4 __attribute__((ext_vector_type(4)));

#define C11 4.8828125e-4f  // 2^-11

union SMem {
  struct {
    _Float16 qh[64][72];   // stride 144B, 16B-aligned
    _Float16 qm[64][72];
    unsigned long long spart[4][64];
  } am;                    // 20480 B
  struct {
    float hl[34][64];
    float abc[34][192];
    float red[4];
  } fu;                    // 34832 B
};

__device__ __forceinline__ unsigned enc_f(float s) {
  unsigned u = __float_as_uint(s);
  return (u & 0x80000000u) ? ~u : (u | 0x80000000u);
}

__device__ __forceinline__ void split2(float x, _Float16& h, _Float16& m) {
  h = (_Float16)x;
  float r1 = x - (float)h;         // exact
  m = (_Float16)(r1 * 2048.0f);    // scaled into fp16 normal range
}

// ---- grid barrier, 2-level arrival ----
// gb[0]             : global counter (own line)
// gb[64 + g*16]     : group counters, g < 32 (128B spacing)
// gb[1024 + b*16]   : per-block release flags, b < 512 (128B spacing)
__device__ __forceinline__ void gbar(unsigned long long* gb, unsigned bar) {
  __shared__ int win;
  __syncthreads();
  if (threadIdx.x == 0) {
    win = 0;
    __threadfence();  // release: make this block's writes agent-visible
    unsigned long long go =
        atomicAdd(gb + 64 + (blockIdx.x >> 4) * 16, 1ull);
    if (go == (unsigned long long)bar * 16 - 1ull) {
      // last arriver of this 16-block group -> global arrival
      unsigned long long old = atomicAdd(gb, 1ull);
      if (old == (unsigned long long)bar * 32 - 1ull) win = 1;
    }
  }
  __syncthreads();
  if (win) {
    // parallel release: 256 threads x 2 flags, independent lines
    for (int i = threadIdx.x; i < NBLK; i += 256)
      atomicExch(gb + 1024 + i * 16, (unsigned long long)bar);
  } else if (threadIdx.x == 0) {
    unsigned long long* myf = gb + 1024 + blockIdx.x * 16;  // own line
    while (atomicAdd(myf, 0ull) < (unsigned long long)bar)
      __builtin_amdgcn_s_sleep(2);
  }
  __syncthreads();
  if (threadIdx.x == 0) __threadfence();  // acquire: drop stale lines
  __syncthreads();
}

// ---------- setup phase (R17 k_setup body, virtual block id) ----------
__device__ void d_setup(int blk, const float* __restrict__ f,
                        const float* __restrict__ embed,
                        const float* __restrict__ phiw,
                        _Float16* __restrict__ ch, _Float16* __restrict__ cm,
                        float* __restrict__ restAll,
                        float* __restrict__ lossac,
                        unsigned long long* __restrict__ packed,
                        float* __restrict__ phiwT) {
  const int tid = threadIdx.x;
  if (blk < 128) {
    // normalize codebook rows, 2-way split, FRAGMENT ORDER
    int g = blk * 256 + tid;  // 4 lanes per code
    int v = g >> 2;
    int sub = g & 3;
    const float* row = embed + v * 64 + sub * 16;
    float x[16];
    float ss = 0.f;
#pragma unroll
    for (int i = 0; i < 16; i += 4) {
      float4 t = *(const float4*)(row + i);
      x[i] = t.x; x[i + 1] = t.y; x[i + 2] = t.z; x[i + 3] = t.w;
      ss += t.x * t.x + t.y * t.y + t.z * t.z + t.w * t.w;
    }
    ss += __shfl_xor(ss, 1);
    ss += __shfl_xor(ss, 2);
    float rinv = 1.0f / fmaxf(sqrtf(ss), 1e-12f);
    _Float16 hb[16], mb[16];
#pragma unroll
    for (int i = 0; i < 16; i++) split2(x[i] * rinv, hb[i], mb[i]);
    const int kc = sub >> 1;
    const int q0 = (2 * sub) & 3;
    const int q1 = (2 * sub + 1) & 3;
    const int m = v & 15;
    const int blkbase = ((v >> 4) * 2 + kc) * 512;
    *(half8*)(ch + blkbase + (q0 * 16 + m) * 8) = *(half8*)(hb);
    *(half8*)(ch + blkbase + (q1 * 16 + m) * 8) = *(half8*)(hb + 8);
    *(half8*)(cm + blkbase + (q0 * 16 + m) * 8) = *(half8*)(mb);
    *(half8*)(cm + blkbase + (q1 * 16 + m) * 8) = *(half8*)(mb + 8);
  } else if (blk < 640) {
    // scale-0 downsample: rest0[c*32 + b] = sum_l f[b][c][l]
    int sb = blk - 128;
    int b = sb >> 4;
    int c = (sb & 15) * 4 + (tid >> 6);
    int lane = tid & 63;
    const float* row = f + (b * 64 + c) * 512 + lane * 8;
    float4 x0 = *(const float4*)row;
    float4 x1 = *(const float4*)(row + 4);
    float ssum = ((x0.x + x0.y) + (x0.z + x0.w)) +
                 ((x1.x + x1.y) + (x1.z + x1.w));
#pragma unroll
    for (int off = 32; off > 0; off >>= 1) ssum += __shfl_down(ssum, off);
    if (lane == 0) restAll[c * 32 + b] = ssum;
  } else {
    int zg = (blk - 640) * 256 + tid;
    const int ZS = 512 * 256;
    for (int i = zg; i < 126976; i += ZS) restAll[2048 + i] = 0.0f;
    for (int i = zg; i < 32736; i += ZS) packed[i] = 0ull;
    if (zg < 5120) lossac[zg] = 0.0f;
    // phiw [p][o][c][t] -> phiwT [p][t][c][o]
    for (int i = zg; i < 49152; i += ZS) {
      float v = phiw[i];
      int p = i / 12288;
      int r = i - p * 12288;
      int o = r / 192;
      int r2 = r - o * 192;
      int c = r2 / 3;
      int t = r2 - c * 3;
      phiwT[((p * 3 + t) * 64 + c) * 64 + o] = v;
    }
  }
}

// ---------- argmax phase ----------
#define ARG_LOAD(BH0, BH1, BM0, BM1, TT)                                   \
  {                                                                        \
    const _Float16* p1 = ch + (code_start + (TT)) * 64 + lane * 8;         \
    const _Float16* p2 = cm + (code_start + (TT)) * 64 + lane * 8;         \
    BH0 = *(const half8*)(p1);                                             \
    BH1 = *(const half8*)(p1 + 512);                                       \
    BM0 = *(const half8*)(p2);                                             \
    BM1 = *(const half8*)(p2 + 512);                                       \
  }

#define ARG_TILE(BH0, BH1, BM0, BM1, TT)                                   \
  {                                                                        \
    const int cid = code_start + (TT) + m;                                 \
    _Pragma("unroll") for (int mt = 0; mt < MT; mt++) {                    \
      f32x4 a0, a1;                                                        \
      a0 = __builtin_amdgcn_mfma_f32_16x16x32_f16(ahf[mt][0], BH0, Z, 0, 0, 0); \
      a1 = __builtin_amdgcn_mfma_f32_16x16x32_f16(ahf[mt][0], BM0, Z, 0, 0, 0); \
      a1 = __builtin_amdgcn_mfma_f32_16x16x32_f16(amf[mt][0], BH0, a1, 0, 0, 0); \
      a0 = __builtin_amdgcn_mfma_f32_16x16x32_f16(ahf[mt][1], BH1, a0, 0, 0, 0); \
      a1 = __builtin_amdgcn_mfma_f32_16x16x32_f16(ahf[mt][1], BM1, a1, 0, 0, 0); \
      a1 = __builtin_amdgcn_mfma_f32_16x16x32_f16(amf[mt][1], BH1, a1, 0, 0, 0); \
      _Pragma("unroll") for (int r = 0; r < 4; r++) {                      \
        float sc = fmaf(C11, a1[r], a0[r]);                                \
        if (sc > best[mt][r]) { best[mt][r] = sc; bidx[mt][r] = cid; }     \
      }                                                                    \
    }                                                                      \
  }

template <int MT>
__device__ void d_argmax(SMem* sm, const _Float16* __restrict__ ch,
                         const _Float16* __restrict__ cm,
                         const float* __restrict__ restq,
                         unsigned long long* __restrict__ packedq, int Q,
                         int mgroups, int nsplit, int wave_codes) {
  const int mg = blockIdx.x % mgroups;
  const int sp0 = blockIdx.x / mgroups;
  if (sp0 >= nsplit) return;  // idle block (block-uniform)
  const int lane = threadIdx.x & 63;
  const int wave = threadIdx.x >> 6;
  const int qbase = mg * (MT * 16);
  for (int i = threadIdx.x; i < MT * 16 * 64; i += 256) {
    int c = i / (MT * 16);
    int qq = i % (MT * 16);
    float v = restq[c * Q + qbase + qq];
    _Float16 h, m;
    split2(v, h, m);
    sm->am.qh[qq][c] = h;
    sm->am.qm[qq][c] = m;
  }
  __syncthreads();

  const int m = lane & 15;
  const int quad = lane >> 4;
  half8 ahf[MT][2], amf[MT][2];
#pragma unroll
  for (int mt = 0; mt < MT; mt++)
#pragma unroll
    for (int kc = 0; kc < 2; kc++) {
      ahf[mt][kc] = *(const half8*)(&sm->am.qh[mt * 16 + m][kc * 32 + quad * 8]);
      amf[mt][kc] = *(const half8*)(&sm->am.qm[mt * 16 + m][kc * 32 + quad * 8]);
    }

  float best[MT][4];
  int bidx[MT][4];
#pragma unroll
  for (int mt = 0; mt < MT; mt++)
#pragma unroll
    for (int r = 0; r < 4; r++) { best[mt][r] = -3.4e38f; bidx[mt][r] = 0; }

  const f32x4 Z = {0.f, 0.f, 0.f, 0.f};
  const int spstride = NBLK / mgroups;

  for (int sp = sp0; sp < nsplit; sp += spstride) {
    const int code_start = (sp * 4 + wave) * wave_codes;
    // depth-2 software pipeline, two named buffer sets
    half8 Ah0, Ah1, Am0, Am1, Bh0, Bh1, Bm0, Bm1;
    ARG_LOAD(Ah0, Ah1, Am0, Am1, 0);
    if (16 < wave_codes) ARG_LOAD(Bh0, Bh1, Bm0, Bm1, 16);
    for (int t = 0; t < wave_codes; t += 32) {
      ARG_TILE(Ah0, Ah1, Am0, Am1, t);
      if (t + 32 < wave_codes) ARG_LOAD(Ah0, Ah1, Am0, Am1, t + 32);
      if (t + 16 < wave_codes) {
        ARG_TILE(Bh0, Bh1, Bm0, Bm1, t + 16);
        if (t + 48 < wave_codes) ARG_LOAD(Bh0, Bh1, Bm0, Bm1, t + 48);
      }
    }
  }

#pragma unroll
  for (int off = 1; off < 16; off <<= 1) {
#pragma unroll
    for (int mt = 0; mt < MT; mt++)
#pragma unroll
      for (int r = 0; r < 4; r++) {
        float ob = __shfl_xor(best[mt][r], off);
        int oi = __shfl_xor(bidx[mt][r], off);
        if (ob > best[mt][r] || (ob == best[mt][r] && oi < bidx[mt][r])) {
          best[mt][r] = ob; bidx[mt][r] = oi;
        }
      }
  }
  if (m == 0) {
#pragma unroll
    for (int mt = 0; mt < MT; mt++)
#pragma unroll
      for (int r = 0; r < 4; r++) {
        unsigned long long pk =
            ((unsigned long long)enc_f(best[mt][r]) << 32) |
            (unsigned)(~bidx[mt][r]);
        sm->am.spart[wave][mt * 16 + quad * 4 + r] = pk;
      }
  }
  __syncthreads();
  if (threadIdx.x < MT * 16) {
    unsigned long long v = sm->am.spart[0][threadIdx.x];
    unsigned long long v1 = sm->am.spart[1][threadIdx.x];
    unsigned long long v2 = sm->am.spart[2][threadIdx.x];
    unsigned long long v3 = sm->am.spart[3][threadIdx.x];
    if (v1 > v) v = v1;
    if (v2 > v) v = v2;
    if (v3 > v) v = v3;
    atomicMax(&packedq[qbase + threadIdx.x], v);
  }
}

// ---------- fused phase (R17 k_fused body, flat block id) ----------
__device__ void d_fused(SMem* sm, const float* __restrict__ f,
                        const float* __restrict__ embed,
                        const float* __restrict__ phib,
                        const float* __restrict__ wT,
                        const unsigned long long* __restrict__ packedq,
                        float* __restrict__ restn, float* __restrict__ fhat,
                        float* __restrict__ lossac, int s, int log2blk,
                        int pidx, int si, int log2blkn) {
  const int ch0 = (blockIdx.x & 15) * 32;
  const int bb = blockIdx.x >> 4;
  const int tid = threadIdx.x;
  const int blkw = 1 << log2blk;
  int j_lo = (ch0 >> log2blk) - 1;
  if (j_lo < 0) j_lo = 0;
  int j_hi = ((ch0 + 31) >> log2blk) + 1;
  if (j_hi > s - 1) j_hi = s - 1;
  const int nseg = j_hi - j_lo + 1;  // <= 34

  for (int i = tid; i < nseg * 64; i += 256) {
    int seg = i >> 6, c = i & 63;
    int idx = (int)(~(unsigned)(packedq[bb * s + j_lo + seg]));
    sm->fu.hl[seg][c] = embed[idx * 64 + c];
  }
  __syncthreads();

  // matvec: lane o owns output channel o; waves stride over segments
  {
    const int o = tid & 63;
    const int w4 = tid >> 6;
    const float* wtp = wT + pidx * 12288 + o;  // [t][c][o]
    float acc[9][3];
#pragma unroll
    for (int a = 0; a < 9; a++) { acc[a][0] = acc[a][1] = acc[a][2] = 0.f; }
#pragma unroll
    for (int c4b = 0; c4b < 4; c4b++) {
      float w48[48];
      const float* wp = wtp + c4b * 16 * 64;
#pragma unroll
      for (int cc = 0; cc < 16; cc++)
#pragma unroll
        for (int k = 0; k < 3; k++)
          w48[cc * 3 + k] = wp[(k * 64 + cc) * 64];
#pragma unroll
      for (int sx = 0; sx < 9; sx++) {
        int seg = w4 + sx * 4;
        if (seg < nseg) {
#pragma unroll
          for (int cc4 = 0; cc4 < 4; cc4++) {
            float4 h4 = *(const float4*)(&sm->fu.hl[seg][c4b * 16 + cc4 * 4]);
            const float hv[4] = {h4.x, h4.y, h4.z, h4.w};
#pragma unroll
            for (int u = 0; u < 4; u++) {
              int cc = cc4 * 4 + u;
              acc[sx][0] = fmaf(w48[cc * 3 + 0], hv[u], acc[sx][0]);
              acc[sx][1] = fmaf(w48[cc * 3 + 1], hv[u], acc[sx][1]);
              acc[sx][2] = fmaf(w48[cc * 3 + 2], hv[u], acc[sx][2]);
            }
          }
        }
      }
    }
#pragma unroll
    for (int sx = 0; sx < 9; sx++) {
      int seg = w4 + sx * 4;
      if (seg < nseg) {
        sm->fu.abc[seg][o] = acc[sx][0];
        sm->fu.abc[seg][64 + o] = acc[sx][1];
        sm->fu.abc[seg][128 + o] = acc[sx][2];
      }
    }
  }
  __syncthreads();

  // apply: thread = (c, 8 consecutive l)
  const int c = tid >> 2;
  const int l0 = ch0 + (tid & 3) * 8;
  const float bias = phib[pidx * 64 + c];
  const int fi0 = (bb * 64 + c) * 512 + l0;
  const float4 fa = *(const float4*)(f + fi0);
  const float4 fb2 = *(const float4*)(f + fi0 + 4);
  float fv[8] = {fa.x, fa.y, fa.z, fa.w, fb2.x, fb2.y, fb2.z, fb2.w};
  float fhv[8] = {0.f, 0.f, 0.f, 0.f, 0.f, 0.f, 0.f, 0.f};
  if (si != 0) {
    const float4 ga = *(const float4*)(fhat + fi0);
    const float4 gb2 = *(const float4*)(fhat + fi0 + 4);
    fhv[0] = ga.x; fhv[1] = ga.y; fhv[2] = ga.z; fhv[3] = ga.w;
    fhv[4] = gb2.x; fhv[5] = gb2.y; fhv[6] = gb2.z; fhv[7] = gb2.w;
  }
  float dv[8];
  float sq = 0.f;
#pragma unroll
  for (int k = 0; k < 8; k++) {
    int l = l0 + k;
    int j = l >> log2blk;
    int jrel = j - j_lo;
    int pos = l & (blkw - 1);
    float y = sm->fu.abc[jrel][64 + c] + bias;
    if (pos == 0) {
      if (j > 0) y += sm->fu.abc[jrel - 1][c];
    } else {
      y += sm->fu.abc[jrel][c];
    }
    if (pos == blkw - 1) {
      if (j < s - 1) y += sm->fu.abc[jrel + 1][128 + c];
    } else {
      y += sm->fu.abc[jrel][128 + c];
    }
    float ho = 0.5f * (sm->fu.hl[jrel][c] + y);
    float fh = fhv[k] + ho;
    fhv[k] = fh;
    float d = fh - fv[k];
    dv[k] = d;
    sq = fmaf(d, d, sq);
  }
  *(float4*)(fhat + fi0) = make_float4(fhv[0], fhv[1], fhv[2], fhv[3]);
  *(float4*)(fhat + fi0 + 4) = make_float4(fhv[4], fhv[5], fhv[6], fhv[7]);

  // next-scale rest: in-wave pre-merge; plain stores when single-block-owned
  if (log2blkn >= 0) {
    const int sn = 512 >> log2blkn;
    const int blkn = 1 << log2blkn;
    const int qb = c * (32 * sn) + bb * sn;
    float rs8 = -(((dv[0] + dv[1]) + (dv[2] + dv[3])) +
                  ((dv[4] + dv[5]) + (dv[6] + dv[7])));
    if (blkn >= 64) {
      float r = rs8;
      r += __shfl_down(r, 2);
      r += __shfl_down(r, 1);
      if ((tid & 3) == 0) atomicAdd(&restn[qb + (l0 >> log2blkn)], r);
    } else if (blkn == 32) {
      float r = rs8;
      r += __shfl_down(r, 2);
      r += __shfl_down(r, 1);
      if ((tid & 3) == 0) restn[qb + (l0 >> 5)] = r;
    } else if (blkn == 16) {
      float r = rs8;
      r += __shfl_down(r, 1);
      if ((tid & 1) == 0) restn[qb + (l0 >> 4)] = r;
    } else if (blkn == 8) {
      restn[qb + (l0 >> 3)] = rs8;
    } else {
      for (int base = 0; base < 8; base += blkn) {
        float rs = 0.f;
        for (int k = 0; k < blkn; k++) rs += dv[base + k];
        restn[qb + ((l0 + base) >> log2blkn)] = -rs;
      }
    }
  }

  // loss partial: per-block slot
#pragma unroll
  for (int off = 32; off > 0; off >>= 1) sq += __shfl_down(sq, off);
  const int lane = tid & 63, wave = tid >> 6;
  if (lane == 0) sm->fu.red[wave] = sq;
  __syncthreads();
  if (tid == 0)
    lossac[si * 512 + blockIdx.x] =
        (sm->fu.red[0] + sm->fu.red[1]) + (sm->fu.red[2] + sm->fu.red[3]);
}

// ---------- loss phase (block 0) ----------
__device__ void d_loss(SMem* sm, const float* __restrict__ lossac,
                       float* __restrict__ out) {
  const int tid = threadIdx.x;
  float sum = 0.f;
  for (int i = tid; i < 5120; i += 256) sum += lossac[i];
#pragma unroll
  for (int off = 32; off > 0; off >>= 1) sum += __shfl_down(sum, off);
  if ((tid & 63) == 0) sm->fu.red[tid >> 6] = sum;
  __syncthreads();
  if (tid == 0)
    out[B_ * C_ * L_] = ((sm->fu.red[0] + sm->fu.red[1]) +
                         (sm->fu.red[2] + sm->fu.red[3])) *
                        (1.25f / (10.0f * (float)(B_ * C_ * L_)));
}

// ---------- megakernel ----------
__global__ __launch_bounds__(256, 2) void k_mega(
    const float* __restrict__ f, const float* __restrict__ embed,
    const float* __restrict__ phiw, const float* __restrict__ phib,
    _Float16* __restrict__ ch, _Float16* __restrict__ cm,
    float* __restrict__ restAll, float* __restrict__ lossac,
    unsigned long long* __restrict__ packed, float* __restrict__ phiwT,
    unsigned long long* __restrict__ gb, float* __restrict__ fhat) {
  __shared__ SMem sm;
  unsigned bar = 0;

  for (int vb = blockIdx.x; vb < 1152; vb += NBLK)
    d_setup(vb, f, embed, phiw, ch, cm, restAll, lossac, packed, phiwT);
  gbar(gb, ++bar);

  for (int si = 0; si < 10; si++) {
    const int s = 1 << si;
    const int Q = 32 * s;
    const int nsplit = (si <= 7) ? 16 : ((si == 8) ? 8 : 4);
    const int wave_codes = V_ / nsplit / 4;
    const int pidx = (si >= 7) ? 3 : ((si >= 5) ? 2 : ((si >= 2) ? 1 : 0));
    const float* restq = restAll + 2048 * (s - 1);
    unsigned long long* pq = packed + 32 * (s - 1);

    if (Q >= 64)
      d_argmax<4>(&sm, ch, cm, restq, pq, Q, Q / 64, nsplit, wave_codes);
    else
      d_argmax<2>(&sm, ch, cm, restq, pq, Q, 1, nsplit, wave_codes);
    gbar(gb, ++bar);

    float* restn = (si < 9) ? (restAll + 2048 * (2 * s - 1)) : nullptr;
    d_fused(&sm, f, embed, phib, phiwT, pq, restn, fhat, lossac, s, 9 - si,
            pidx, si, (si < 9) ? (8 - si) : -1);
    gbar(gb, ++bar);
  }

  if (blockIdx.x == 0) d_loss(&sm, lossac, fhat);
}

extern "C" void kernel_launch(void* const* d_in, const int* in_sizes, int n_in,
                              void* d_out, int out_size, void* d_ws,
                              size_t ws_size, hipStream_t stream) {
  const float* f     = (const float*)d_in[0];  // [32][64][512]
  const float* embed = (const float*)d_in[1];  // [8192][64]
  const float* phiw  = (const float*)d_in[2];  // [4][64][64][3]
  const float* phib  = (const float*)d_in[3];  // [4][64]
  float* fhat = (float*)d_out;                 // f_hat + loss at [1048576]

  _Float16* ch = (_Float16*)d_ws;                  // V*64 f16 (fragment order)
  _Float16* cm = ch + V_ * 64;                     // V*64 f16 (fragment order)
  float* restAll = (float*)(cm + V_ * 64);         // 2048*1023 floats
  float* lossac = restAll + 2048 * 1023;           // 5120 ([10][512] slots)
  unsigned long long* packed = (unsigned long long*)(lossac + 5120);  // 32736
  float* phiwT = (float*)(packed + 32736);         // 4*3*64*64 = 49152 floats
  unsigned long long* gbarmem = (unsigned long long*)(phiwT + 49152);
  // layout: [0] global cnt; [64+g*16] group cnts (g<32); [1024+b*16] flags
  const size_t GB_ULL = 1024 + NBLK * 16;  // 9216 ull = 73728 B

  // barrier state must start at 0 each replay (graph includes this node)
  hipMemsetAsync(gbarmem, 0, GB_ULL * sizeof(unsigned long long), stream);

  k_mega<<<dim3(NBLK), dim3(256), 0, stream>>>(
      f, embed, phiw, phib, ch, cm, restAll, lossac, packed, phiwT, gbarmem,
      fhat);
}

// Round 15
// 515.090 us; speedup vs baseline: 1.5326x; 1.5326x over previous
//
#include <hip/hip_runtime.h>

// VectorQuantizer (VAR-style multi-scale residual VQ) forward on gfx950.
// R21 (FINAL): exact revert to R17, the session's verified best (518.2us).
// R18-R20 priced the megakernel alternative: three different grid-barrier
// implementations (shared-flag, per-block-flag, hierarchical arrival) all
// cost ~20us/barrier -> the irreducible part is the agent-scope
// __threadfence across 8 non-coherent XCDs, not the counter protocol.
// 21 barriers x 20us (420us) > 22 dispatch gaps x ~9us (190us): the HW
// dispatcher IS the cheaper sync for this dependency chain.
// Session ladder 816->518: depth-2 ILP pipeline (R10, -14% argmax),
// fragment-order codebook packing (R16, 88.6->68.4us si9, fixes 16-line
// TA gather serialization), same-address atomic elimination (R15 argmax
// LDS-merge + nsplit cut, -160us; R17 loss slots + restn plain stores,
// -51us). Recurring MI355X lesson: same-line device atomics and
// agent-scope fences stall with ALL pipes idle -- invisible in util
// counters, visible only through accounting gaps.

#define B_ 32
#define C_ 64
#define L_ 512
#define V_ 8192

typedef _Float16 half8 __attribute__((ext_vector_type(8)));
typedef float f32x4 __attribute__((ext_vector_type(4)));

#define C11 4.8828125e-4f  // 2^-11

__device__ __forceinline__ unsigned enc_f(float s) {
  unsigned u = __float_as_uint(s);
  return (u & 0x80000000u) ? ~u : (u | 0x80000000u);
}

__device__ __forceinline__ void split2(float x, _Float16& h, _Float16& m) {
  h = (_Float16)x;
  float r1 = x - (float)h;         // exact
  m = (_Float16)(r1 * 2048.0f);    // scaled into fp16 normal range
}

// ---------- setup: codebook prep + zeroing + downsample + weight transpose ----------
__global__ __launch_bounds__(256) void k_setup(
    const float* __restrict__ f, const float* __restrict__ embed,
    const float* __restrict__ phiw, _Float16* __restrict__ ch,
    _Float16* __restrict__ cm, float* __restrict__ restAll,
    float* __restrict__ lossac, unsigned long long* __restrict__ packed,
    float* __restrict__ phiwT) {
  const int blk = blockIdx.x;
  const int tid = threadIdx.x;
  if (blk < 128) {
    // normalize codebook rows (fp32), 2-way split, write in FRAGMENT ORDER:
    // ch[((v>>4)*2 + kc)*512 + (quad*16 + (v&15))*8 + j]
    int g = blk * 256 + tid;  // 4 lanes per code
    int v = g >> 2;
    int sub = g & 3;          // halfs sub*16 .. sub*16+15
    const float* row = embed + v * 64 + sub * 16;
    float x[16];
    float ss = 0.f;
#pragma unroll
    for (int i = 0; i < 16; i += 4) {
      float4 t = *(const float4*)(row + i);
      x[i] = t.x; x[i + 1] = t.y; x[i + 2] = t.z; x[i + 3] = t.w;
      ss += t.x * t.x + t.y * t.y + t.z * t.z + t.w * t.w;
    }
    ss += __shfl_xor(ss, 1);
    ss += __shfl_xor(ss, 2);
    float rinv = 1.0f / fmaxf(sqrtf(ss), 1e-12f);
    _Float16 hb[16], mb[16];
#pragma unroll
    for (int i = 0; i < 16; i++) split2(x[i] * rinv, hb[i], mb[i]);
    const int kc = sub >> 1;
    const int q0 = (2 * sub) & 3;
    const int q1 = (2 * sub + 1) & 3;
    const int m = v & 15;
    const int blkbase = ((v >> 4) * 2 + kc) * 512;
    *(half8*)(ch + blkbase + (q0 * 16 + m) * 8) = *(half8*)(hb);
    *(half8*)(ch + blkbase + (q1 * 16 + m) * 8) = *(half8*)(hb + 8);
    *(half8*)(cm + blkbase + (q0 * 16 + m) * 8) = *(half8*)(mb);
    *(half8*)(cm + blkbase + (q1 * 16 + m) * 8) = *(half8*)(mb + 8);
  } else if (blk < 640) {
    // scale-0 downsample: rest0[c*32 + b] = sum_l f[b][c][l]
    int sb = blk - 128;  // 512 blocks: 32 b x 16 c-groups
    int b = sb >> 4;
    int c = (sb & 15) * 4 + (tid >> 6);
    int lane = tid & 63;
    const float* row = f + (b * 64 + c) * 512 + lane * 8;
    float4 x0 = *(const float4*)row;
    float4 x1 = *(const float4*)(row + 4);
    float ssum = ((x0.x + x0.y) + (x0.z + x0.w)) +
                 ((x1.x + x1.y) + (x1.z + x1.w));
#pragma unroll
    for (int off = 32; off > 0; off >>= 1) ssum += __shfl_down(ssum, off);
    if (lane == 0) restAll[c * 32 + b] = ssum;
  } else {
    // zero: atomic rest slices, packed, lossac + weight transpose
    int zg = (blk - 640) * 256 + tid;
    const int ZS = 512 * 256;
    for (int i = zg; i < 126976; i += ZS) restAll[2048 + i] = 0.0f;
    for (int i = zg; i < 32736; i += ZS) packed[i] = 0ull;
    if (zg < 5120) lossac[zg] = 0.0f;
    if (phiwT) {
      // phiw [p][o][c][t] -> phiwT [p][t][c][o]; coalesced read, scattered write
      for (int i = zg; i < 49152; i += ZS) {
        float v = phiw[i];
        int p = i / 12288;
        int r = i - p * 12288;
        int o = r / 192;
        int r2 = r - o * 192;
        int c = r2 / 3;
        int t = r2 - c * 3;
        phiwT[((p * 3 + t) * 64 + c) * 64 + o] = v;
      }
    }
  }
}

// ---------- MFMA argmax: fragment-order coalesced loads, LDS-merged atomics ----------
#define ARG_LOAD(BH0, BH1, BM0, BM1, TT)                                   \
  {                                                                        \
    const _Float16* p1 = ch + (code_start + (TT)) * 64 + lane * 8;         \
    const _Float16* p2 = cm + (code_start + (TT)) * 64 + lane * 8;         \
    BH0 = *(const half8*)(p1);                                             \
    BH1 = *(const half8*)(p1 + 512);                                       \
    BM0 = *(const half8*)(p2);                                             \
    BM1 = *(const half8*)(p2 + 512);                                       \
  }

#define ARG_TILE(BH0, BH1, BM0, BM1, TT)                                   \
  {                                                                        \
    const int cid = cs_g + (TT) + m;                                       \
    _Pragma("unroll") for (int mt = 0; mt < MT; mt++) {                    \
      f32x4 a0, a1;                                                        \
      a0 = __builtin_amdgcn_mfma_f32_16x16x32_f16(ah[mt][0], BH0, Z, 0, 0, 0); \
      a1 = __builtin_amdgcn_mfma_f32_16x16x32_f16(ah[mt][0], BM0, Z, 0, 0, 0); \
      a1 = __builtin_amdgcn_mfma_f32_16x16x32_f16(am[mt][0], BH0, a1, 0, 0, 0); \
      a0 = __builtin_amdgcn_mfma_f32_16x16x32_f16(ah[mt][1], BH1, a0, 0, 0, 0); \
      a1 = __builtin_amdgcn_mfma_f32_16x16x32_f16(ah[mt][1], BM1, a1, 0, 0, 0); \
      a1 = __builtin_amdgcn_mfma_f32_16x16x32_f16(am[mt][1], BH1, a1, 0, 0, 0); \
      _Pragma("unroll") for (int r = 0; r < 4; r++) {                      \
        float sc = fmaf(C11, a1[r], a0[r]);                                \
        if (sc > best[mt][r]) { best[mt][r] = sc; bidx[mt][r] = cid; }     \
      }                                                                    \
    }                                                                      \
  }

template <int MT>
__global__ __launch_bounds__(256, 2) void k_argmax3(
    const _Float16* __restrict__ ch, const _Float16* __restrict__ cm,
    const float* __restrict__ restq, unsigned long long* __restrict__ packedq,
    int Q, int mgroups, int wave_codes, int cbase) {
  const int mg = blockIdx.x % mgroups;
  const int sp = blockIdx.x / mgroups;
  const int lane = threadIdx.x & 63;
  const int wave = threadIdx.x >> 6;
  const int qbase = mg * (MT * 16);
  __shared__ _Float16 qh[MT * 16][72];  // stride 144B, 16B-aligned
  __shared__ _Float16 qm[MT * 16][72];
  __shared__ unsigned long long spart[4][MT * 16];
  for (int i = threadIdx.x; i < MT * 16 * 64; i += 256) {
    int c = i / (MT * 16);
    int qq = i % (MT * 16);
    float v = restq[c * Q + qbase + qq];
    _Float16 h, m;
    split2(v, h, m);
    qh[qq][c] = h;
    qm[qq][c] = m;
  }
  __syncthreads();

  const int m = lane & 15;
  const int quad = lane >> 4;
  half8 ah[MT][2], am[MT][2];
#pragma unroll
  for (int mt = 0; mt < MT; mt++)
#pragma unroll
    for (int kc = 0; kc < 2; kc++) {
      ah[mt][kc] = *(const half8*)(&qh[mt * 16 + m][kc * 32 + quad * 8]);
      am[mt][kc] = *(const half8*)(&qm[mt * 16 + m][kc * 32 + quad * 8]);
    }

  float best[MT][4];
  int bidx[MT][4];
#pragma unroll
  for (int mt = 0; mt < MT; mt++)
#pragma unroll
    for (int r = 0; r < 4; r++) { best[mt][r] = -3.4e38f; bidx[mt][r] = 0; }

  const int code_start = (sp * 4 + wave) * wave_codes;
  const int cs_g = cbase + code_start;
  const f32x4 Z = {0.f, 0.f, 0.f, 0.f};

  // depth-2 software pipeline, two named buffer sets (no rotation copies)
  half8 Ah0, Ah1, Am0, Am1, Bh0, Bh1, Bm0, Bm1;
  ARG_LOAD(Ah0, Ah1, Am0, Am1, 0);
  if (16 < wave_codes) ARG_LOAD(Bh0, Bh1, Bm0, Bm1, 16);
  for (int t = 0; t < wave_codes; t += 32) {
    ARG_TILE(Ah0, Ah1, Am0, Am1, t);
    if (t + 32 < wave_codes) ARG_LOAD(Ah0, Ah1, Am0, Am1, t + 32);
    if (t + 16 < wave_codes) {
      ARG_TILE(Bh0, Bh1, Bm0, Bm1, t + 16);
      if (t + 48 < wave_codes) ARG_LOAD(Bh0, Bh1, Bm0, Bm1, t + 48);
    }
  }

#pragma unroll
  for (int off = 1; off < 16; off <<= 1) {
#pragma unroll
    for (int mt = 0; mt < MT; mt++)
#pragma unroll
      for (int r = 0; r < 4; r++) {
        float ob = __shfl_xor(best[mt][r], off);
        int oi = __shfl_xor(bidx[mt][r], off);
        if (ob > best[mt][r] || (ob == best[mt][r] && oi < bidx[mt][r])) {
          best[mt][r] = ob; bidx[mt][r] = oi;
        }
      }
  }
  // per-wave results -> LDS
  if (m == 0) {
#pragma unroll
    for (int mt = 0; mt < MT; mt++)
#pragma unroll
      for (int r = 0; r < 4; r++) {
        unsigned long long pk =
            ((unsigned long long)enc_f(best[mt][r]) << 32) |
            (unsigned)(~bidx[mt][r]);
        spart[wave][mt * 16 + quad * 4 + r] = pk;
      }
  }
  __syncthreads();
  // cross-wave merge in LDS; ONE coalesced atomicMax per query per block
  if (threadIdx.x < MT * 16) {
    unsigned long long v = spart[0][threadIdx.x];
    unsigned long long v1 = spart[1][threadIdx.x];
    unsigned long long v2 = spart[2][threadIdx.x];
    unsigned long long v3 = spart[3][threadIdx.x];
    if (v1 > v) v = v1;
    if (v2 > v) v = v2;
    if (v3 > v) v = v3;
    atomicMax(&packedq[qbase + threadIdx.x], v);
  }
}

// ---------- fused: per-block matvec (+halo) -> apply -> loss + next rest ----------
__global__ __launch_bounds__(256) void k_fused(
    const float* __restrict__ f, const float* __restrict__ embed,
    const float* __restrict__ phiw, const float* __restrict__ phib,
    const float* __restrict__ wT, const unsigned long long* __restrict__ packedq,
    float* __restrict__ restn, float* __restrict__ fhat,
    float* __restrict__ lossac, int s, int log2blk, int pidx, int si,
    int log2blkn) {
  const int ch0 = blockIdx.x * 32;
  const int bb = blockIdx.y;
  const int tid = threadIdx.x;
  const int blkw = 1 << log2blk;
  int j_lo = (ch0 >> log2blk) - 1;
  if (j_lo < 0) j_lo = 0;
  int j_hi = ((ch0 + 31) >> log2blk) + 1;
  if (j_hi > s - 1) j_hi = s - 1;
  const int nseg = j_hi - j_lo + 1;  // <= 34

  __shared__ float hl[34][64];
  __shared__ float abc_l[34][192];

  for (int i = tid; i < nseg * 64; i += 256) {
    int seg = i >> 6, c = i & 63;
    int idx = (int)(~(unsigned)(packedq[bb * s + j_lo + seg]));
    hl[seg][c] = embed[idx * 64 + c];
  }
  __syncthreads();

  // matvec: lane o owns output channel o; waves stride over segments
  {
    const int o = tid & 63;
    const int w4 = tid >> 6;
    const float* wrow = phiw + (pidx * 64 + o) * 192;      // [o][c][t] row
    const float* wtp = wT ? (wT + pidx * 12288 + o) : nullptr;  // [t][c][o]
    float acc[9][3];
#pragma unroll
    for (int a = 0; a < 9; a++) { acc[a][0] = acc[a][1] = acc[a][2] = 0.f; }
#pragma unroll
    for (int c4b = 0; c4b < 4; c4b++) {
      float w48[48];
      if (wT) {
        // coalesced: lane-varying index (o) is innermost, stride 4B
        const float* wp = wtp + c4b * 16 * 64;
#pragma unroll
        for (int cc = 0; cc < 16; cc++)
#pragma unroll
          for (int k = 0; k < 3; k++)
            w48[cc * 3 + k] = wp[(k * 64 + cc) * 64];
      } else {
#pragma unroll
        for (int k = 0; k < 12; k++)
          *(float4*)(w48 + 4 * k) = *(const float4*)(wrow + c4b * 48 + 4 * k);
      }
#pragma unroll
      for (int sx = 0; sx < 9; sx++) {
        int seg = w4 + sx * 4;
        if (seg < nseg) {
#pragma unroll
          for (int cc4 = 0; cc4 < 4; cc4++) {
            float4 h4 = *(const float4*)(&hl[seg][c4b * 16 + cc4 * 4]);
            const float hv[4] = {h4.x, h4.y, h4.z, h4.w};
#pragma unroll
            for (int u = 0; u < 4; u++) {
              int cc = cc4 * 4 + u;
              acc[sx][0] = fmaf(w48[cc * 3 + 0], hv[u], acc[sx][0]);
              acc[sx][1] = fmaf(w48[cc * 3 + 1], hv[u], acc[sx][1]);
              acc[sx][2] = fmaf(w48[cc * 3 + 2], hv[u], acc[sx][2]);
            }
          }
        }
      }
    }
#pragma unroll
    for (int sx = 0; sx < 9; sx++) {
      int seg = w4 + sx * 4;
      if (seg < nseg) {
        abc_l[seg][o] = acc[sx][0];
        abc_l[seg][64 + o] = acc[sx][1];
        abc_l[seg][128 + o] = acc[sx][2];
      }
    }
  }
  __syncthreads();

  // apply: thread = (c, 8 consecutive l)
  const int c = tid >> 2;
  const int l0 = ch0 + (tid & 3) * 8;
  const float bias = phib[pidx * 64 + c];
  const int fi0 = (bb * 64 + c) * 512 + l0;
  const float4 fa = *(const float4*)(f + fi0);
  const float4 fb2 = *(const float4*)(f + fi0 + 4);
  float fv[8] = {fa.x, fa.y, fa.z, fa.w, fb2.x, fb2.y, fb2.z, fb2.w};
  float fhv[8] = {0.f, 0.f, 0.f, 0.f, 0.f, 0.f, 0.f, 0.f};
  if (si != 0) {
    const float4 ga = *(const float4*)(fhat + fi0);
    const float4 gb2 = *(const float4*)(fhat + fi0 + 4);
    fhv[0] = ga.x; fhv[1] = ga.y; fhv[2] = ga.z; fhv[3] = ga.w;
    fhv[4] = gb2.x; fhv[5] = gb2.y; fhv[6] = gb2.z; fhv[7] = gb2.w;
  }
  float dv[8];
  float sq = 0.f;
#pragma unroll
  for (int k = 0; k < 8; k++) {
    int l = l0 + k;
    int j = l >> log2blk;
    int jrel = j - j_lo;
    int pos = l & (blkw - 1);
    float y = abc_l[jrel][64 + c] + bias;
    if (pos == 0) {
      if (j > 0) y += abc_l[jrel - 1][c];
    } else {
      y += abc_l[jrel][c];
    }
    if (pos == blkw - 1) {
      if (j < s - 1) y += abc_l[jrel + 1][128 + c];
    } else {
      y += abc_l[jrel][128 + c];
    }
    float ho = 0.5f * (hl[jrel][c] + y);
    float fh = fhv[k] + ho;
    fhv[k] = fh;
    float d = fh - fv[k];
    dv[k] = d;
    sq = fmaf(d, d, sq);
  }
  *(float4*)(fhat + fi0) = make_float4(fhv[0], fhv[1], fhv[2], fhv[3]);
  *(float4*)(fhat + fi0 + 4) = make_float4(fhv[4], fhv[5], fhv[6], fhv[7]);

  // next-scale rest (sums; argmax is scale-invariant in the query).
  // 4-lane in-wave pre-merge; plain stores when a single block owns
  // the address (blkn<=32); atomicAdd only for blkn>=64 (<=8 writers).
  if (log2blkn >= 0) {
    const int sn = 512 >> log2blkn;
    const int blkn = 1 << log2blkn;
    const int qb = c * (32 * sn) + bb * sn;
    float rs8 = -(((dv[0] + dv[1]) + (dv[2] + dv[3])) +
                  ((dv[4] + dv[5]) + (dv[6] + dv[7])));
    if (blkn >= 64) {
      float r = rs8;
      r += __shfl_down(r, 2);
      r += __shfl_down(r, 1);
      if ((tid & 3) == 0) atomicAdd(&restn[qb + (l0 >> log2blkn)], r);
    } else if (blkn == 32) {
      float r = rs8;
      r += __shfl_down(r, 2);
      r += __shfl_down(r, 1);
      if ((tid & 3) == 0) restn[qb + (l0 >> 5)] = r;
    } else if (blkn == 16) {
      float r = rs8;
      r += __shfl_down(r, 1);
      if ((tid & 1) == 0) restn[qb + (l0 >> 4)] = r;
    } else if (blkn == 8) {
      restn[qb + (l0 >> 3)] = rs8;
    } else {
      for (int base = 0; base < 8; base += blkn) {
        float rs = 0.f;
        for (int k = 0; k < blkn; k++) rs += dv[base + k];
        restn[qb + ((l0 + base) >> log2blkn)] = -rs;
      }
    }
  }

  // loss partial: per-block slot, no cross-block atomic
#pragma unroll
  for (int off = 32; off > 0; off >>= 1) sq += __shfl_down(sq, off);
  __shared__ float red[4];
  const int lane = tid & 63, wave = tid >> 6;
  if (lane == 0) red[wave] = sq;
  __syncthreads();
  if (tid == 0)
    lossac[si * 512 + bb * 16 + blockIdx.x] =
        (red[0] + red[1]) + (red[2] + red[3]);
}

// ---------- final loss ----------
__global__ __launch_bounds__(256) void k_loss(const float* __restrict__ lossac,
                                              float* __restrict__ out) {
  const int tid = threadIdx.x;
  float sum = 0.f;
  for (int i = tid; i < 5120; i += 256) sum += lossac[i];
#pragma unroll
  for (int off = 32; off > 0; off >>= 1) sum += __shfl_down(sum, off);
  __shared__ float red[4];
  if ((tid & 63) == 0) red[tid >> 6] = sum;
  __syncthreads();
  if (tid == 0)
    out[B_ * C_ * L_] = ((red[0] + red[1]) + (red[2] + red[3])) *
                        (1.25f / (10.0f * (float)(B_ * C_ * L_)));
}

extern "C" void kernel_launch(void* const* d_in, const int* in_sizes, int n_in,
                              void* d_out, int out_size, void* d_ws,
                              size_t ws_size, hipStream_t stream) {
  const float* f     = (const float*)d_in[0];  // [32][64][512]
  const float* embed = (const float*)d_in[1];  // [8192][64]
  const float* phiw  = (const float*)d_in[2];  // [4][64][64][3]
  const float* phib  = (const float*)d_in[3];  // [4][64]
  float* fhat = (float*)d_out;                 // f_hat + loss at [1048576]

  _Float16* ch = (_Float16*)d_ws;                  // V*64 f16 (fragment order)
  _Float16* cm = ch + V_ * 64;                     // V*64 f16 (fragment order)
  float* restAll = (float*)(cm + V_ * 64);         // 2048*1023 floats
  float* lossac = restAll + 2048 * 1023;           // 5120 ([10][512] slots)
  unsigned long long* packed = (unsigned long long*)(lossac + 5120);  // 32736
  float* phiwT = (float*)(packed + 32736);         // 4*3*64*64 = 49152 floats
  const size_t WS_NEED = (size_t)((char*)(phiwT + 49152) - (char*)d_ws);
  if (ws_size < WS_NEED) phiwT = nullptr;  // fallback: old gather path

  static const int PIDX[10] = {0, 0, 1, 1, 1, 2, 2, 3, 3, 3};
  static const int NSPL[10] = {16, 16, 16, 16, 16, 16, 16, 16, 8, 4};

  k_setup<<<dim3(1152), dim3(256), 0, stream>>>(f, embed, phiw, ch, cm,
                                                restAll, lossac, packed,
                                                phiwT);

  for (int si = 0; si < 10; si++) {
    const int s = 1 << si;
    const int Q = 32 * s;
    const int log2blk = 9 - si;
    const int nsplit = NSPL[si];
    const int wave_codes = V_ / nsplit / 4;
    const float* restq = restAll + 2048 * (s - 1);
    unsigned long long* pq = packed + 32 * (s - 1);

    if (Q >= 64) {
      const int mgroups = Q / 64;
      k_argmax3<4><<<dim3(mgroups * nsplit), dim3(256), 0, stream>>>(
          ch, cm, restq, pq, Q, mgroups, wave_codes, 0);
    } else {
      k_argmax3<2><<<dim3(nsplit), dim3(256), 0, stream>>>(
          ch, cm, restq, pq, Q, 1, wave_codes, 0);
    }

    float* restn = (si < 9) ? (restAll + 2048 * (2 * s - 1)) : nullptr;
    const int log2blkn = (si < 9) ? (8 - si) : -1;
    k_fused<<<dim3(16, 32), dim3(256), 0, stream>>>(
        f, embed, phiw, phib, phiwT, pq, restn, fhat, lossac, s, log2blk,
        PIDX[si], si, log2blkn);
  }
  k_loss<<<dim3(1), dim3(256), 0, stream>>>(lossac, fhat);
}